// Round 7
// baseline (409.824 us; speedup 1.0000x reference)
//
#include <hip/hip_runtime.h>
#include <math.h>

#define NROWS   65536
#define DIMS    64
#define KCODES  1024
#define XL      132   // LDS x stride (pad)

typedef float f32x2 __attribute__((ext_vector_type(2)));
typedef float f32x4 __attribute__((ext_vector_type(4)));

static constexpr size_t QST_OFF  = 0;         // quantized_st [65536*64]
static constexpr size_t LOSS_OFF = 4194304;   // loss scalar
static constexpr size_t PERP_OFF = 4194305;   // perplexity scalar
static constexpr size_t ENC_OFF  = 4194306;   // encodings [65536*1024]
static constexpr size_t IDX_OFF  = 71303170;  // encoding_indices [65536]
static constexpr size_t DIST_OFF = 71368706;  // distances [65536*1024]

// ||e_k||^2 per np.sum(np.square(emb),0): sequential d, mul then add (no fma).
__global__ void enorm_kernel(const float* __restrict__ emb, float* __restrict__ enorm) {
    #pragma clang fp contract(off)
    int k = blockIdx.x * blockDim.x + threadIdx.x;   // 0..1023
    float s = 0.f;
    for (int d = 0; d < DIMS; ++d) {
        float e  = emb[(size_t)d * KCODES + k];
        float sq = e * e;
        s = s + sq;
    }
    enorm[k] = s;
}

// Block = 128 rows x 512 k (kb half). 256 thr, 8x8 reg tile. x in LDS (only),
// e read per-d from global (L2-resident), dist/enc via nontemporal stores,
// no barriers in the k/d loops -> blocks free-run and pipes overlap.
__global__ __launch_bounds__(256, 3) void vq_dist(
    const float* __restrict__ x, const float* __restrict__ emb,
    const float* __restrict__ enorm, float* __restrict__ out,
    unsigned long long* __restrict__ winners)
{
    #pragma clang fp contract(off)
    __shared__ __align__(16) float xs[DIMS * XL];   // [d][row], 33.8 KB
    __shared__ float xn[128];

    const int tid = threadIdx.x;
    const int tc  = tid & 15;          // k-group: 8 k
    const int tr  = tid >> 4;          // row-group: rows tr*8..+7
    const int kb  = blockIdx.x & 1;    // k half
    const int rb  = blockIdx.x >> 1;   // row tile
    const size_t n0 = (size_t)rb * 128;
    const float* xg = x + n0 * DIMS;

    // stage x transposed: contiguous float4 loads, scalar transposed LDS writes
    #pragma unroll
    for (int i = 0; i < 8; ++i) {
        int c = i * 256 + tid;             // float4 index 0..2047
        int row = c >> 4, q = c & 15;
        float4 v = *(const float4*)(xg + (size_t)row * DIMS + q * 4);
        xs[(q * 4 + 0) * XL + row] = v.x;
        xs[(q * 4 + 1) * XL + row] = v.y;
        xs[(q * 4 + 2) * XL + row] = v.z;
        xs[(q * 4 + 3) * XL + row] = v.w;
    }
    __syncthreads();
    // ||x||^2: numpy pairwise (8 accs, mul-then-add, 3-level combine)
    if (tid < 128) {
        float rr[8];
        #pragma unroll
        for (int j = 0; j < 8; ++j) { float v = xs[j * XL + tid]; rr[j] = v * v; }
        for (int i = 8; i < 64; i += 8)
            #pragma unroll
            for (int j = 0; j < 8; ++j) { float v = xs[(i + j) * XL + tid]; float sq = v * v; rr[j] = rr[j] + sq; }
        xn[tid] = ((rr[0] + rr[1]) + (rr[2] + rr[3])) + ((rr[4] + rr[5]) + (rr[6] + rr[7]));
    }
    __syncthreads();   // last barrier — k/d loops below are barrier-free

    float bv[8]; int bi[8];
    #pragma unroll
    for (int j = 0; j < 8; ++j) { bv[j] = 3.4e38f; bi[j] = 0; }

    for (int kt = 0; kt < 4; ++kt) {
        const int kbase = kb * 512 + kt * 128 + tc * 8;
        float acc[8][8];
        #pragma unroll
        for (int j = 0; j < 8; ++j)
            #pragma unroll
            for (int m = 0; m < 8; ++m) acc[j][m] = 0.f;

        // e prefetch d=0
        const float* ebase = emb + kbase;
        float4 eA = *(const float4*)(ebase);
        float4 eB = *(const float4*)(ebase + 4);
        #pragma unroll 4
        for (int d = 0; d < DIMS; ++d) {
            float4 eAn, eBn;
            if (d < DIMS - 1) {
                const float* ep = ebase + (size_t)(d + 1) * KCODES;
                eAn = *(const float4*)(ep);
                eBn = *(const float4*)(ep + 4);
            }
            float4 x0 = *(const float4*)&xs[d * XL + tr * 8];       // rows 0..3 (broadcast)
            float4 x1 = *(const float4*)&xs[d * XL + tr * 8 + 4];   // rows 4..7
            const float xv[8] = {x0.x, x0.y, x0.z, x0.w, x1.x, x1.y, x1.z, x1.w};
            #pragma unroll
            for (int j = 0; j < 8; ++j) {
                acc[j][0] = fmaf(xv[j], eA.x, acc[j][0]);
                acc[j][1] = fmaf(xv[j], eA.y, acc[j][1]);
                acc[j][2] = fmaf(xv[j], eA.z, acc[j][2]);
                acc[j][3] = fmaf(xv[j], eA.w, acc[j][3]);
                acc[j][4] = fmaf(xv[j], eB.x, acc[j][4]);
                acc[j][5] = fmaf(xv[j], eB.y, acc[j][5]);
                acc[j][6] = fmaf(xv[j], eB.z, acc[j][6]);
                acc[j][7] = fmaf(xv[j], eB.w, acc[j][7]);
            }
            eA = eAn; eB = eBn;
        }

        const float4 enA = *(const float4*)(enorm + kbase);
        const float4 enB = *(const float4*)(enorm + kbase + 4);
        const float en[8] = {enA.x, enA.y, enA.z, enA.w, enB.x, enB.y, enB.z, enB.w};

        #pragma unroll
        for (int j = 0; j < 8; ++j) {
            const int row = tr * 8 + j;
            const float xnr = xn[row];
            float dv[8];
            #pragma unroll
            for (int m = 0; m < 8; ++m) {   // np order: (xn - 2*M) + en, each rounded
                float mm = 2.0f * acc[j][m];
                float tt = xnr - mm;
                dv[m] = tt + en[m];
            }
            const size_t rowg = n0 + row;
            float* dr = out + DIST_OFF + rowg * (size_t)KCODES + kbase;
            f32x2 v01 = {dv[0], dv[1]}, v23 = {dv[2], dv[3]};
            f32x2 v45 = {dv[4], dv[5]}, v67 = {dv[6], dv[7]};
            __builtin_nontemporal_store(v01, (f32x2*)(dr));
            __builtin_nontemporal_store(v23, (f32x2*)(dr + 2));
            __builtin_nontemporal_store(v45, (f32x2*)(dr + 4));
            __builtin_nontemporal_store(v67, (f32x2*)(dr + 6));
            float* er = out + ENC_OFF + rowg * (size_t)KCODES + kbase;
            const f32x2 z2 = {0.f, 0.f};
            __builtin_nontemporal_store(z2, (f32x2*)(er));
            __builtin_nontemporal_store(z2, (f32x2*)(er + 2));
            __builtin_nontemporal_store(z2, (f32x2*)(er + 4));
            __builtin_nontemporal_store(z2, (f32x2*)(er + 6));

            // local argmin, ascending k; strict less across kt keeps earliest k
            float lv = dv[0]; int li = kbase;
            #pragma unroll
            for (int m = 1; m < 8; ++m) if (dv[m] < lv) { lv = dv[m]; li = kbase + m; }
            if (lv < bv[j]) { bv[j] = lv; bi[j] = li; }
        }
    }

    // per-row reduce across the 16 tc lanes (contiguous): u64 key = exact
    // float order, smaller-k tie-break; then cross-block atomicMin.
    #pragma unroll
    for (int j = 0; j < 8; ++j) {
        int ib = __float_as_int(bv[j]);
        unsigned mk = (unsigned)ib ^ ((unsigned)(ib >> 31) | 0x80000000u);
        unsigned long long key = ((unsigned long long)mk << 32) | (unsigned)bi[j];
        #pragma unroll
        for (int m = 1; m < 16; m <<= 1) {
            unsigned long long ok = __shfl_xor(key, m);
            if (ok < key) key = ok;
        }
        if (tc == 0) atomicMin(&winners[n0 + tr * 8 + j], key);
    }
}

// Pass 2: unpack winners -> qst gather, idx, enc one-hot, counts, sqsum
__global__ __launch_bounds__(256) void vq_finish(
    const float* __restrict__ x, const float* __restrict__ emb,
    const unsigned long long* __restrict__ winners, float* __restrict__ out,
    float* __restrict__ counts, float* __restrict__ sqsum)
{
    __shared__ float bsum[4];
    const int tid = threadIdx.x;
    const size_t row = (size_t)blockIdx.x * 16 + (tid >> 4);
    const int q = tid & 15;
    const int k = (int)(winners[row] & 1023u);

    f32x4 e4;
    e4.x = emb[(size_t)(q * 4 + 0) * KCODES + k];
    e4.y = emb[(size_t)(q * 4 + 1) * KCODES + k];
    e4.z = emb[(size_t)(q * 4 + 2) * KCODES + k];
    e4.w = emb[(size_t)(q * 4 + 3) * KCODES + k];
    float4 x4 = *(const float4*)(x + row * DIMS + q * 4);
    __builtin_nontemporal_store(e4, (f32x4*)(out + QST_OFF + row * DIMS + q * 4));

    float f0 = e4.x - x4.x, f1 = e4.y - x4.y, f2 = e4.z - x4.z, f3 = e4.w - x4.w;
    float ls = f0 * f0 + f1 * f1 + f2 * f2 + f3 * f3;
    #pragma unroll
    for (int m = 1; m < 64; m <<= 1) ls += __shfl_xor(ls, m);
    if ((tid & 63) == 0) bsum[tid >> 6] = ls;

    if (q == 0) {
        out[IDX_OFF + row] = (float)k;
        atomicAdd(&counts[k], 1.0f);
        out[ENC_OFF + row * (size_t)KCODES + k] = 1.0f;   // zeros by vq_dist (prior kernel)
    }
    __syncthreads();
    if (tid == 0) atomicAdd(sqsum, (bsum[0] + bsum[1]) + (bsum[2] + bsum[3]));
}

__global__ void vq_final(const float* __restrict__ counts, const float* __restrict__ sqsum,
                         float* __restrict__ out) {
    __shared__ double part[16];
    int tid = threadIdx.x;  // 1024 threads
    double p = (double)counts[tid] * (1.0 / 65536.0);
    double t = p * log(p + 1e-10);
    #pragma unroll
    for (int m = 1; m < 64; m <<= 1) t += __shfl_xor(t, m);
    if ((tid & 63) == 0) part[tid >> 6] = t;
    __syncthreads();
    if (tid == 0) {
        double s = 0.0;
        #pragma unroll
        for (int i = 0; i < 16; ++i) s += part[i];
        out[LOSS_OFF] = (float)(1.25 * (double)sqsum[0] * (1.0 / 4194304.0));
        out[PERP_OFF] = (float)exp(-s);
    }
}

extern "C" void kernel_launch(void* const* d_in, const int* in_sizes, int n_in,
                              void* d_out, int out_size, void* d_ws, size_t ws_size,
                              hipStream_t stream) {
    const float* x   = (const float*)d_in[0];   // (64,32,32,64) fp32
    const float* emb = (const float*)d_in[1];   // (64,1024) fp32
    float* out = (float*)d_out;
    // ws (floats): enorm[0,1024) | counts[1024,2048) | sqsum[2048] |
    // winners u64 at float-offset 4096 (512 KB)
    float* enorm  = (float*)d_ws;
    float* counts = enorm + KCODES;
    float* sqsum  = counts + KCODES;
    unsigned long long* winners = (unsigned long long*)((float*)d_ws + 4096);

    hipMemsetAsync(counts, 0, (KCODES + 1) * sizeof(float), stream);
    hipMemsetAsync(winners, 0xFF, NROWS * sizeof(unsigned long long), stream);
    enorm_kernel<<<KCODES / 256, 256, 0, stream>>>(emb, enorm);
    vq_dist<<<(NROWS / 128) * 2, 256, 0, stream>>>(x, emb, enorm, out, winners);
    vq_finish<<<NROWS / 16, 256, 0, stream>>>(x, emb, winners, out, counts, sqsum);
    vq_final<<<1, KCODES, 0, stream>>>(counts, sqsum, out);
}